// Round 1
// baseline (2492.862 us; speedup 1.0000x reference)
//
#include <hip/hip_runtime.h>
#include <hip/hip_bf16.h>

#define D_MODEL 1024
#define D_FF    4096
#define N_EXPERTS 8
#define TOPK    2
#define T_TOK   4096
#define NPAIR   (T_TOK * TOPK)   // 8192
#define MT_MAX  32               // ceil(T_TOK / 128)

__device__ __forceinline__ float gelu_tanh(float v) {
    // jax.nn.gelu default (approximate=True)
    float u = 0.7978845608028654f * (v + 0.044715f * v * v * v);
    return 0.5f * v * (1.0f + tanhf(u));
}

// ---------------------------------------------------------------- router
// one wave per token: logits over 8 experts, softmax, top-2
__global__ __launch_bounds__(256) void router_kernel(
    const float* __restrict__ x, const float* __restrict__ Wg,
    int* __restrict__ top_e, float* __restrict__ top_w,
    int* __restrict__ counts)
{
    int wave = threadIdx.x >> 6;
    int lane = threadIdx.x & 63;
    int t = blockIdx.x * 4 + wave;
    if (t >= T_TOK) return;

    float acc[8] = {0.f,0.f,0.f,0.f,0.f,0.f,0.f,0.f};
    const float* xr = x + (size_t)t * D_MODEL;
    for (int d = lane; d < D_MODEL; d += 64) {
        float xv = xr[d];
        const float* wr = Wg + d * N_EXPERTS;
        float4 w0 = *(const float4*)wr;
        float4 w1 = *(const float4*)(wr + 4);
        acc[0] += xv * w0.x; acc[1] += xv * w0.y;
        acc[2] += xv * w0.z; acc[3] += xv * w0.w;
        acc[4] += xv * w1.x; acc[5] += xv * w1.y;
        acc[6] += xv * w1.z; acc[7] += xv * w1.w;
    }
    #pragma unroll
    for (int off = 32; off >= 1; off >>= 1) {
        #pragma unroll
        for (int e = 0; e < 8; e++) acc[e] += __shfl_xor(acc[e], off);
    }
    if (lane == 0) {
        float m = acc[0];
        #pragma unroll
        for (int e = 1; e < 8; e++) m = fmaxf(m, acc[e]);
        float p[8]; float s = 0.f;
        #pragma unroll
        for (int e = 0; e < 8; e++) { p[e] = expf(acc[e] - m); s += p[e]; }
        float inv = 1.f / s;
        #pragma unroll
        for (int e = 0; e < 8; e++) p[e] *= inv;
        // top-2, ties -> lowest index first (matches jax.lax.top_k)
        int i0 = 0; float b0 = p[0];
        #pragma unroll
        for (int e = 1; e < 8; e++) if (p[e] > b0) { b0 = p[e]; i0 = e; }
        int i1 = -1; float b1 = -1.f;
        #pragma unroll
        for (int e = 0; e < 8; e++) if (e != i0 && p[e] > b1) { b1 = p[e]; i1 = e; }
        top_e[2*t]   = i0; top_w[2*t]   = b0;
        top_e[2*t+1] = i1; top_w[2*t+1] = b1;
        atomicAdd(&counts[i0], 1);
        atomicAdd(&counts[i1], 1);
    }
}

// ---------------------------------------------------------------- offsets
__global__ void offsets_kernel(const int* __restrict__ counts, int* __restrict__ offsets)
{
    if (threadIdx.x == 0 && blockIdx.x == 0) {
        int run = 0;
        for (int e = 0; e < N_EXPERTS; e++) { offsets[e] = run; run += counts[e]; }
        offsets[N_EXPERTS] = run;
    }
}

// ---------------------------------------------------------------- scatter
__global__ __launch_bounds__(256) void scatter_kernel(
    const int* __restrict__ top_e, const int* __restrict__ offsets,
    int* __restrict__ counts2, int* __restrict__ pair_id)
{
    int t = blockIdx.x * blockDim.x + threadIdx.x;
    if (t >= T_TOK) return;
    #pragma unroll
    for (int k = 0; k < TOPK; k++) {
        int e = top_e[2*t + k];
        int pos = atomicAdd(&counts2[e], 1);
        pair_id[offsets[e] + pos] = 2*t + k;
    }
}

// ---------------------------------------------------------------- GEMM1
// h[pair_row, 0:4096] = gelu(x[token] @ W1[e] + b1[e]); A gathered, C -> bf16
__global__ __launch_bounds__(256) void gemm1_kernel(
    const float* __restrict__ x, const float* __restrict__ W1,
    const float* __restrict__ b1,
    const int* __restrict__ offsets, const int* __restrict__ pair_id,
    __hip_bfloat16* __restrict__ h)
{
    int e  = blockIdx.y >> 5;
    int mt = blockIdx.y & 31;
    int off_e = offsets[e];
    int cnt   = offsets[e + 1] - off_e;
    int m0 = mt * 128;
    if (m0 >= cnt) return;
    int n0 = blockIdx.x * 128;

    __shared__ float As[16][132];
    __shared__ float Bs[16][132];
    __shared__ int pid[128];

    int tid = threadIdx.x;
    if (tid < 128) {
        int r = m0 + tid; if (r >= cnt) r = cnt - 1;
        pid[tid] = pair_id[off_e + r];
    }
    __syncthreads();

    int tx = tid & 15, ty = tid >> 4;
    float acc[2][2][4][4] = {};

    const float* Wb = W1 + (size_t)e * D_MODEL * D_FF;
    int arow  = tid >> 1;
    int akoff = (tid & 1) * 8;
    int brow  = tid >> 4;             // 0..15
    int bcol  = (tid & 15) * 8;
    const float* xrow = x + (size_t)(pid[arow] >> 1) * D_MODEL;

    for (int k0 = 0; k0 < D_MODEL; k0 += 16) {
        float4 av0 = *(const float4*)(xrow + k0 + akoff);
        float4 av1 = *(const float4*)(xrow + k0 + akoff + 4);
        const float* bp = Wb + (size_t)(k0 + brow) * D_FF + n0 + bcol;
        float4 bv0 = *(const float4*)bp;
        float4 bv1 = *(const float4*)(bp + 4);
        As[akoff+0][arow] = av0.x; As[akoff+1][arow] = av0.y;
        As[akoff+2][arow] = av0.z; As[akoff+3][arow] = av0.w;
        As[akoff+4][arow] = av1.x; As[akoff+5][arow] = av1.y;
        As[akoff+6][arow] = av1.z; As[akoff+7][arow] = av1.w;
        *(float4*)&Bs[brow][bcol]     = bv0;
        *(float4*)&Bs[brow][bcol + 4] = bv1;
        __syncthreads();
        #pragma unroll
        for (int kk = 0; kk < 16; ++kk) {
            float4 a0 = *(const float4*)&As[kk][ty*4];
            float4 a1 = *(const float4*)&As[kk][64 + ty*4];
            float4 c0 = *(const float4*)&Bs[kk][tx*4];
            float4 c1 = *(const float4*)&Bs[kk][64 + tx*4];
            float av[2][4] = {{a0.x,a0.y,a0.z,a0.w},{a1.x,a1.y,a1.z,a1.w}};
            float bv[2][4] = {{c0.x,c0.y,c0.z,c0.w},{c1.x,c1.y,c1.z,c1.w}};
            #pragma unroll
            for (int im = 0; im < 2; im++)
            #pragma unroll
            for (int in = 0; in < 2; in++)
            #pragma unroll
            for (int i = 0; i < 4; i++)
            #pragma unroll
            for (int j = 0; j < 4; j++)
                acc[im][in][i][j] += av[im][i] * bv[in][j];
        }
        __syncthreads();
    }

    #pragma unroll
    for (int im = 0; im < 2; im++)
    #pragma unroll
    for (int i = 0; i < 4; i++) {
        int r = im*64 + ty*4 + i;
        if (m0 + r < cnt) {
            size_t hbase = (size_t)(off_e + m0 + r) * D_FF;
            #pragma unroll
            for (int in = 0; in < 2; in++)
            #pragma unroll
            for (int j = 0; j < 4; j++) {
                int n = n0 + in*64 + tx*4 + j;
                float v = acc[im][in][i][j] + b1[e * D_FF + n];
                h[hbase + n] = __float2bfloat16(gelu_tanh(v));
            }
        }
    }
}

// ---------------------------------------------------------------- GEMM2
// y[pair_id, 0:1024] = h[pair_row] @ W2[e] + b2[e]
__global__ __launch_bounds__(256) void gemm2_kernel(
    const __hip_bfloat16* __restrict__ h, const float* __restrict__ W2,
    const float* __restrict__ b2,
    const int* __restrict__ offsets, const int* __restrict__ pair_id,
    float* __restrict__ y)
{
    int e  = blockIdx.y >> 5;
    int mt = blockIdx.y & 31;
    int off_e = offsets[e];
    int cnt   = offsets[e + 1] - off_e;
    int m0 = mt * 128;
    if (m0 >= cnt) return;
    int n0 = blockIdx.x * 128;

    __shared__ float As[16][132];
    __shared__ float Bs[16][132];
    __shared__ int pid[128];

    int tid = threadIdx.x;
    if (tid < 128) {
        int r = m0 + tid; if (r >= cnt) r = cnt - 1;
        pid[tid] = pair_id[off_e + r];
    }
    __syncthreads();

    int tx = tid & 15, ty = tid >> 4;
    float acc[2][2][4][4] = {};

    const float* Wb = W2 + (size_t)e * D_FF * D_MODEL;
    int arow  = tid >> 1;
    int akoff = (tid & 1) * 8;
    int brow  = tid >> 4;
    int bcol  = (tid & 15) * 8;
    int ar = m0 + arow; if (ar >= cnt) ar = cnt - 1;
    const __hip_bfloat16* hrow = h + (size_t)(off_e + ar) * D_FF;

    for (int k0 = 0; k0 < D_FF; k0 += 16) {
        union { uint4 u; __hip_bfloat16 b[8]; } av;
        av.u = *(const uint4*)(hrow + k0 + akoff);
        const float* bp = Wb + (size_t)(k0 + brow) * D_MODEL + n0 + bcol;
        float4 bv0 = *(const float4*)bp;
        float4 bv1 = *(const float4*)(bp + 4);
        #pragma unroll
        for (int i = 0; i < 8; i++) As[akoff + i][arow] = __bfloat162float(av.b[i]);
        *(float4*)&Bs[brow][bcol]     = bv0;
        *(float4*)&Bs[brow][bcol + 4] = bv1;
        __syncthreads();
        #pragma unroll
        for (int kk = 0; kk < 16; ++kk) {
            float4 a0 = *(const float4*)&As[kk][ty*4];
            float4 a1 = *(const float4*)&As[kk][64 + ty*4];
            float4 c0 = *(const float4*)&Bs[kk][tx*4];
            float4 c1 = *(const float4*)&Bs[kk][64 + tx*4];
            float av2[2][4] = {{a0.x,a0.y,a0.z,a0.w},{a1.x,a1.y,a1.z,a1.w}};
            float bv2[2][4] = {{c0.x,c0.y,c0.z,c0.w},{c1.x,c1.y,c1.z,c1.w}};
            #pragma unroll
            for (int im = 0; im < 2; im++)
            #pragma unroll
            for (int in = 0; in < 2; in++)
            #pragma unroll
            for (int i = 0; i < 4; i++)
            #pragma unroll
            for (int j = 0; j < 4; j++)
                acc[im][in][i][j] += av2[im][i] * bv2[in][j];
        }
        __syncthreads();
    }

    #pragma unroll
    for (int im = 0; im < 2; im++)
    #pragma unroll
    for (int i = 0; i < 4; i++) {
        int r = im*64 + ty*4 + i;
        if (m0 + r < cnt) {
            int p = pid[r];
            size_t ybase = (size_t)p * D_MODEL;
            #pragma unroll
            for (int in = 0; in < 2; in++) {
                int n = n0 + in*64 + tx*4;
                float4 v;
                v.x = acc[im][in][i][0] + b2[e * D_MODEL + n + 0];
                v.y = acc[im][in][i][1] + b2[e * D_MODEL + n + 1];
                v.z = acc[im][in][i][2] + b2[e * D_MODEL + n + 2];
                v.w = acc[im][in][i][3] + b2[e * D_MODEL + n + 3];
                *(float4*)(y + ybase + n) = v;
            }
        }
    }
}

// ---------------------------------------------------------------- combine
__global__ __launch_bounds__(256) void combine_kernel(
    const float* __restrict__ y, const float* __restrict__ top_w,
    float* __restrict__ out)
{
    int gid = blockIdx.x * blockDim.x + threadIdx.x;   // T_TOK*256 threads
    int t = gid >> 8;
    int c = gid & 255;
    float w0 = top_w[2*t];
    float w1 = top_w[2*t + 1];
    const float4* y0 = (const float4*)(y + (size_t)(2*t) * D_MODEL);
    const float4* y1 = (const float4*)(y + (size_t)(2*t + 1) * D_MODEL);
    float4 a = y0[c], b = y1[c];
    float4 o;
    o.x = w0*a.x + w1*b.x; o.y = w0*a.y + w1*b.y;
    o.z = w0*a.z + w1*b.z; o.w = w0*a.w + w1*b.w;
    ((float4*)out)[gid] = o;
}

// ---------------------------------------------------------------- launch
extern "C" void kernel_launch(void* const* d_in, const int* in_sizes, int n_in,
                              void* d_out, int out_size, void* d_ws, size_t ws_size,
                              hipStream_t stream)
{
    const float* x  = (const float*)d_in[0];
    const float* Wg = (const float*)d_in[1];
    const float* W1 = (const float*)d_in[2];
    const float* b1 = (const float*)d_in[3];
    const float* W2 = (const float*)d_in[4];
    const float* b2 = (const float*)d_in[5];
    float* out = (float*)d_out;

    char* ws = (char*)d_ws;
    // layout
    int*   top_e   = (int*)(ws + 0);                       // NPAIR ints
    float* top_w   = (float*)(ws + (size_t)NPAIR * 4);     // NPAIR floats
    int*   counts  = (int*)(ws + (size_t)NPAIR * 8);       // small block (256 B)
    int*   counts2 = counts + N_EXPERTS;
    int*   offsets = counts2 + N_EXPERTS;                  // E+1
    int*   pair_id = (int*)(ws + (size_t)NPAIR * 8 + 256); // NPAIR ints
    char*  hbase   = ws + (size_t)NPAIR * 8 + 256 + (size_t)NPAIR * 4;
    __hip_bfloat16* h = (__hip_bfloat16*)hbase;            // NPAIR * D_FF bf16
    float* y = (float*)(hbase + (size_t)NPAIR * D_FF * 2); // NPAIR * D_MODEL f32

    hipMemsetAsync(counts, 0, 256, stream);

    router_kernel<<<T_TOK / 4, 256, 0, stream>>>(x, Wg, top_e, top_w, counts);
    offsets_kernel<<<1, 64, 0, stream>>>(counts, offsets);
    scatter_kernel<<<T_TOK / 256, 256, 0, stream>>>(top_e, offsets, counts2, pair_id);
    gemm1_kernel<<<dim3(D_FF / 128, N_EXPERTS * MT_MAX), 256, 0, stream>>>(
        x, W1, b1, offsets, pair_id, h);
    gemm2_kernel<<<dim3(D_MODEL / 128, N_EXPERTS * MT_MAX), 256, 0, stream>>>(
        h, W2, b2, offsets, pair_id, y);
    combine_kernel<<<T_TOK, 256, 0, stream>>>(y, top_w, out);
}

// Round 2
// 737.318 us; speedup vs baseline: 3.3810x; 3.3810x over previous
//
#include <hip/hip_runtime.h>
#include <hip/hip_bf16.h>

#define D_MODEL 1024
#define D_FF    4096
#define N_EXPERTS 8
#define TOPK    2
#define T_TOK   4096
#define NPAIR   (T_TOK * TOPK)   // 8192
#define MT_MAX  32               // ceil(T_TOK / 128)

typedef __attribute__((ext_vector_type(8))) short s8v;          // bf16x8 MFMA frag
typedef __attribute__((ext_vector_type(4))) float f4v;          // fp32x4 MFMA acc
typedef __attribute__((ext_vector_type(8))) unsigned short u16x8;

__device__ __forceinline__ void async16(const void* g, void* l) {
    __builtin_amdgcn_global_load_lds(
        (const __attribute__((address_space(1))) void*)g,
        (__attribute__((address_space(3))) void*)l, 16, 0, 0);
}

__device__ __forceinline__ float gelu_tanh(float v) {
    // jax.nn.gelu approximate=True; tanh(u) = 1 - 2/(exp(2u)+1)
    float u = 0.7978845608028654f * (v + 0.044715f * v * v * v);
    float t = 1.0f - 2.0f / (1.0f + __expf(2.0f * u));
    return 0.5f * v * (1.0f + t);
}

__device__ __forceinline__ unsigned short f2bf(float f) {
    union { __hip_bfloat16 b; unsigned short u; } cv;
    cv.b = __float2bfloat16(f);
    return cv.u;
}

// ---------------------------------------------------------------- router
// one wave per token: logits over 8 experts (fp32 for exact top-k), softmax, top-2
__global__ __launch_bounds__(256) void router_kernel(
    const float* __restrict__ x, const float* __restrict__ Wg,
    int* __restrict__ top_e, float* __restrict__ top_w,
    int* __restrict__ counts)
{
    int wave = threadIdx.x >> 6;
    int lane = threadIdx.x & 63;
    int t = blockIdx.x * 4 + wave;
    if (t >= T_TOK) return;

    float acc[8] = {0.f,0.f,0.f,0.f,0.f,0.f,0.f,0.f};
    const float* xr = x + (size_t)t * D_MODEL;
    for (int d = lane; d < D_MODEL; d += 64) {
        float xv = xr[d];
        const float* wr = Wg + d * N_EXPERTS;
        float4 w0 = *(const float4*)wr;
        float4 w1 = *(const float4*)(wr + 4);
        acc[0] += xv * w0.x; acc[1] += xv * w0.y;
        acc[2] += xv * w0.z; acc[3] += xv * w0.w;
        acc[4] += xv * w1.x; acc[5] += xv * w1.y;
        acc[6] += xv * w1.z; acc[7] += xv * w1.w;
    }
    #pragma unroll
    for (int off = 32; off >= 1; off >>= 1) {
        #pragma unroll
        for (int e = 0; e < 8; e++) acc[e] += __shfl_xor(acc[e], off);
    }
    if (lane == 0) {
        float m = acc[0];
        #pragma unroll
        for (int e = 1; e < 8; e++) m = fmaxf(m, acc[e]);
        float p[8]; float s = 0.f;
        #pragma unroll
        for (int e = 0; e < 8; e++) { p[e] = expf(acc[e] - m); s += p[e]; }
        float inv = 1.f / s;
        #pragma unroll
        for (int e = 0; e < 8; e++) p[e] *= inv;
        int i0 = 0; float b0 = p[0];
        #pragma unroll
        for (int e = 1; e < 8; e++) if (p[e] > b0) { b0 = p[e]; i0 = e; }
        int i1 = -1; float b1 = -1.f;
        #pragma unroll
        for (int e = 0; e < 8; e++) if (e != i0 && p[e] > b1) { b1 = p[e]; i1 = e; }
        top_e[2*t]   = i0; top_w[2*t]   = b0;
        top_e[2*t+1] = i1; top_w[2*t+1] = b1;
        atomicAdd(&counts[i0], 1);
        atomicAdd(&counts[i1], 1);
    }
}

// ---------------------------------------------------------------- offsets
__global__ void offsets_kernel(const int* __restrict__ counts, int* __restrict__ offsets)
{
    if (threadIdx.x == 0 && blockIdx.x == 0) {
        int run = 0;
        for (int e = 0; e < N_EXPERTS; e++) { offsets[e] = run; run += counts[e]; }
        offsets[N_EXPERTS] = run;
    }
}

// ---------------------------------------------------------------- scatter
__global__ __launch_bounds__(256) void scatter_kernel(
    const int* __restrict__ top_e, const int* __restrict__ offsets,
    int* __restrict__ counts2, int* __restrict__ pair_id)
{
    int t = blockIdx.x * blockDim.x + threadIdx.x;
    if (t >= T_TOK) return;
    #pragma unroll
    for (int k = 0; k < TOPK; k++) {
        int e = top_e[2*t + k];
        int pos = atomicAdd(&counts2[e], 1);
        pair_id[offsets[e] + pos] = 2*t + k;
    }
}

// ---------------------------------------------------------------- cast x -> bf16
__global__ __launch_bounds__(256) void cast_x_kernel(
    const float* __restrict__ x, __hip_bfloat16* __restrict__ xb)
{
    int i = (blockIdx.x * 256 + threadIdx.x) * 8;
    float4 a = *(const float4*)(x + i);
    float4 b = *(const float4*)(x + i + 4);
    unsigned short t[8];
    t[0]=f2bf(a.x); t[1]=f2bf(a.y); t[2]=f2bf(a.z); t[3]=f2bf(a.w);
    t[4]=f2bf(b.x); t[5]=f2bf(b.y); t[6]=f2bf(b.z); t[7]=f2bf(b.w);
    *(u16x8*)((unsigned short*)xb + i) = *(u16x8*)t;
}

// ------------------------------------------------- transpose-cast W -> [E][N][K] bf16
// src per expert: [R][C] fp32, dst per expert: [C][R] bf16. 64x64 tiles.
__global__ __launch_bounds__(256) void transpose_cast_kernel(
    const float* __restrict__ src, __hip_bfloat16* __restrict__ dst, int R, int C)
{
    int e = blockIdx.z;
    src += (size_t)e * R * C;
    dst += (size_t)e * R * C;
    int b0 = blockIdx.x * 64;   // C-dim tile origin
    int a0 = blockIdx.y * 64;   // R-dim tile origin

    __shared__ float tile[64][65];
    int tid = threadIdx.x;
    int lr = tid >> 4;          // 0..15
    int lc = (tid & 15) * 4;    // 0..60
    #pragma unroll
    for (int rr = 0; rr < 4; rr++) {
        int r = lr + rr * 16;
        *(float4*)&tile[r][lc] = *(const float4*)(src + (size_t)(a0 + r) * C + b0 + lc);
    }
    __syncthreads();
    int oc = tid >> 3;          // 0..31 (C-dim within tile)
    int oj = (tid & 7) * 8;     // 0..56 (R-dim within tile)
    #pragma unroll
    for (int rr = 0; rr < 2; rr++) {
        int c = oc + rr * 32;
        unsigned short t[8];
        #pragma unroll
        for (int j = 0; j < 8; j++) t[j] = f2bf(tile[oj + j][c]);
        *(u16x8*)((unsigned short*)dst + (size_t)(b0 + c) * R + a0 + oj) = *(u16x8*)t;
    }
}

// ---------------------------------------------------------------- GEMM1 (MFMA)
// h[row, n] = gelu(x_bf16[token] @ W1T[e]^T + b1[e]), 128x128 tile, BK=32
__global__ __launch_bounds__(256) void gemm1_mfma(
    const __hip_bfloat16* __restrict__ xb, const __hip_bfloat16* __restrict__ W1T,
    const float* __restrict__ b1,
    const int* __restrict__ offsets, const int* __restrict__ pair_id,
    __hip_bfloat16* __restrict__ h)
{
    int e  = blockIdx.y >> 5;
    int mt = blockIdx.y & 31;
    int off_e = offsets[e];
    int cnt   = offsets[e + 1] - off_e;
    int m0 = mt * 128;
    if (m0 >= cnt) return;
    int n0 = blockIdx.x * 128;

    __shared__ __hip_bfloat16 As[128 * 32];   // [m][k]
    __shared__ __hip_bfloat16 Bs[128 * 32];   // [n][k]
    __shared__ int pid[128];

    int tid = threadIdx.x;
    if (tid < 128) {
        int r = m0 + tid; if (r >= cnt) r = cnt - 1;
        pid[tid] = pair_id[off_e + r];
    }
    __syncthreads();

    int lane = tid & 63, wid = tid >> 6;
    int ia0 = wid * 64 + lane;            // staging linear idx, pass 0
    int ia1 = ia0 + 256;                  // pass 1
    int rA0 = ia0 >> 2, kA0 = (ia0 & 3) * 8;
    int rA1 = ia1 >> 2, kA1 = (ia1 & 3) * 8;

    const __hip_bfloat16* gA0 = xb + (size_t)(pid[rA0] >> 1) * D_MODEL + kA0;
    const __hip_bfloat16* gA1 = xb + (size_t)(pid[rA1] >> 1) * D_MODEL + kA1;
    const __hip_bfloat16* WT  = W1T + (size_t)e * (D_MODEL * D_FF);
    const __hip_bfloat16* gB0 = WT + (size_t)(n0 + rA0) * D_MODEL + kA0;
    const __hip_bfloat16* gB1 = WT + (size_t)(n0 + rA1) * D_MODEL + kA1;

    int fm = lane & 15;
    int fk = (lane >> 4) * 8;
    int wm = (wid >> 1) * 64;
    int wn = (wid & 1) * 64;

    f4v acc[4][4];
    #pragma unroll
    for (int i = 0; i < 4; i++)
        #pragma unroll
        for (int j = 0; j < 4; j++)
            acc[i][j] = (f4v){0.f, 0.f, 0.f, 0.f};

    for (int k0 = 0; k0 < D_MODEL; k0 += 32) {
        async16(gA0 + k0, As + ia0 * 8);
        async16(gA1 + k0, As + ia1 * 8);
        async16(gB0 + k0, Bs + ia0 * 8);
        async16(gB1 + k0, Bs + ia1 * 8);
        __syncthreads();
        s8v af[4], bfr[4];
        #pragma unroll
        for (int i = 0; i < 4; i++)
            af[i] = *(const s8v*)(As + (wm + i * 16 + fm) * 32 + fk);
        #pragma unroll
        for (int j = 0; j < 4; j++)
            bfr[j] = *(const s8v*)(Bs + (wn + j * 16 + fm) * 32 + fk);
        #pragma unroll
        for (int i = 0; i < 4; i++)
            #pragma unroll
            for (int j = 0; j < 4; j++)
                acc[i][j] = __builtin_amdgcn_mfma_f32_16x16x32_bf16(af[i], bfr[j], acc[i][j], 0, 0, 0);
        __syncthreads();
    }

    int rq = (lane >> 4) * 4;   // C/D: row = (lane>>4)*4 + reg, col = lane&15
    #pragma unroll
    for (int i = 0; i < 4; i++) {
        #pragma unroll
        for (int j = 0; j < 4; j++) {
            int n = n0 + wn + j * 16 + fm;
            float bias = b1[e * D_FF + n];
            #pragma unroll
            for (int r = 0; r < 4; r++) {
                int m = wm + i * 16 + rq + r;
                if (m0 + m < cnt) {
                    float v = acc[i][j][r] + bias;
                    h[(size_t)(off_e + m0 + m) * D_FF + n] = __float2bfloat16(gelu_tanh(v));
                }
            }
        }
    }
}

// ---------------------------------------------------------------- GEMM2 (MFMA)
// y[pair, n] = h[row] @ W2T[e]^T + b2[e]
__global__ __launch_bounds__(256) void gemm2_mfma(
    const __hip_bfloat16* __restrict__ h, const __hip_bfloat16* __restrict__ W2T,
    const float* __restrict__ b2,
    const int* __restrict__ offsets, const int* __restrict__ pair_id,
    float* __restrict__ y)
{
    int e  = blockIdx.y >> 5;
    int mt = blockIdx.y & 31;
    int off_e = offsets[e];
    int cnt   = offsets[e + 1] - off_e;
    int m0 = mt * 128;
    if (m0 >= cnt) return;
    int n0 = blockIdx.x * 128;

    __shared__ __hip_bfloat16 As[128 * 32];
    __shared__ __hip_bfloat16 Bs[128 * 32];
    __shared__ int pid[128];

    int tid = threadIdx.x;
    if (tid < 128) {
        int r = m0 + tid; if (r >= cnt) r = cnt - 1;
        pid[tid] = pair_id[off_e + r];
    }
    __syncthreads();

    int lane = tid & 63, wid = tid >> 6;
    int ia0 = wid * 64 + lane;
    int ia1 = ia0 + 256;
    int rA0 = ia0 >> 2, kA0 = (ia0 & 3) * 8;
    int rA1 = ia1 >> 2, kA1 = (ia1 & 3) * 8;
    int mr0 = m0 + rA0; if (mr0 >= cnt) mr0 = cnt - 1;
    int mr1 = m0 + rA1; if (mr1 >= cnt) mr1 = cnt - 1;

    const __hip_bfloat16* gA0 = h + (size_t)(off_e + mr0) * D_FF + kA0;
    const __hip_bfloat16* gA1 = h + (size_t)(off_e + mr1) * D_FF + kA1;
    const __hip_bfloat16* WT  = W2T + (size_t)e * (D_FF * D_MODEL);
    const __hip_bfloat16* gB0 = WT + (size_t)(n0 + rA0) * D_FF + kA0;
    const __hip_bfloat16* gB1 = WT + (size_t)(n0 + rA1) * D_FF + kA1;

    int fm = lane & 15;
    int fk = (lane >> 4) * 8;
    int wm = (wid >> 1) * 64;
    int wn = (wid & 1) * 64;

    f4v acc[4][4];
    #pragma unroll
    for (int i = 0; i < 4; i++)
        #pragma unroll
        for (int j = 0; j < 4; j++)
            acc[i][j] = (f4v){0.f, 0.f, 0.f, 0.f};

    for (int k0 = 0; k0 < D_FF; k0 += 32) {
        async16(gA0 + k0, As + ia0 * 8);
        async16(gA1 + k0, As + ia1 * 8);
        async16(gB0 + k0, Bs + ia0 * 8);
        async16(gB1 + k0, Bs + ia1 * 8);
        __syncthreads();
        s8v af[4], bfr[4];
        #pragma unroll
        for (int i = 0; i < 4; i++)
            af[i] = *(const s8v*)(As + (wm + i * 16 + fm) * 32 + fk);
        #pragma unroll
        for (int j = 0; j < 4; j++)
            bfr[j] = *(const s8v*)(Bs + (wn + j * 16 + fm) * 32 + fk);
        #pragma unroll
        for (int i = 0; i < 4; i++)
            #pragma unroll
            for (int j = 0; j < 4; j++)
                acc[i][j] = __builtin_amdgcn_mfma_f32_16x16x32_bf16(af[i], bfr[j], acc[i][j], 0, 0, 0);
        __syncthreads();
    }

    int rq = (lane >> 4) * 4;
    #pragma unroll
    for (int i = 0; i < 4; i++) {
        #pragma unroll
        for (int j = 0; j < 4; j++) {
            int n = n0 + wn + j * 16 + fm;
            float bias = b2[e * D_MODEL + n];
            #pragma unroll
            for (int r = 0; r < 4; r++) {
                int m = wm + i * 16 + rq + r;
                if (m0 + m < cnt) {
                    int p = pid[m];
                    y[(size_t)p * D_MODEL + n] = acc[i][j][r] + bias;
                }
            }
        }
    }
}

// ---------------------------------------------------------------- combine
__global__ __launch_bounds__(256) void combine_kernel(
    const float* __restrict__ y, const float* __restrict__ top_w,
    float* __restrict__ out)
{
    int gid = blockIdx.x * blockDim.x + threadIdx.x;
    int t = gid >> 8;
    int c = gid & 255;
    float w0 = top_w[2*t];
    float w1 = top_w[2*t + 1];
    const float4* y0 = (const float4*)(y + (size_t)(2*t) * D_MODEL);
    const float4* y1 = (const float4*)(y + (size_t)(2*t + 1) * D_MODEL);
    float4 a = y0[c], b = y1[c];
    float4 o;
    o.x = w0*a.x + w1*b.x; o.y = w0*a.y + w1*b.y;
    o.z = w0*a.z + w1*b.z; o.w = w0*a.w + w1*b.w;
    ((float4*)out)[gid] = o;
}

// ---------------------------------------------------------------- launch
extern "C" void kernel_launch(void* const* d_in, const int* in_sizes, int n_in,
                              void* d_out, int out_size, void* d_ws, size_t ws_size,
                              hipStream_t stream)
{
    const float* x  = (const float*)d_in[0];
    const float* Wg = (const float*)d_in[1];
    const float* W1 = (const float*)d_in[2];
    const float* b1 = (const float*)d_in[3];
    const float* W2 = (const float*)d_in[4];
    const float* b2 = (const float*)d_in[5];
    float* out = (float*)d_out;

    char* ws = (char*)d_ws;
    size_t off = 0;
    int*   top_e   = (int*)(ws + off);  off += (size_t)NPAIR * 4;
    float* top_w   = (float*)(ws + off); off += (size_t)NPAIR * 4;
    int*   counts  = (int*)(ws + off);
    int*   counts2 = counts + N_EXPERTS;
    int*   offsets = counts2 + N_EXPERTS; off += 256;
    int*   pair_id = (int*)(ws + off);  off += (size_t)NPAIR * 4;
    off = (off + 255) & ~(size_t)255;
    __hip_bfloat16* xb  = (__hip_bfloat16*)(ws + off); off += (size_t)T_TOK * D_MODEL * 2;
    __hip_bfloat16* W1T = (__hip_bfloat16*)(ws + off); off += (size_t)N_EXPERTS * D_MODEL * D_FF * 2;
    __hip_bfloat16* W2T = (__hip_bfloat16*)(ws + off); off += (size_t)N_EXPERTS * D_MODEL * D_FF * 2;
    __hip_bfloat16* h   = (__hip_bfloat16*)(ws + off); off += (size_t)NPAIR * D_FF * 2;
    float*          y   = (float*)(ws + off);          off += (size_t)NPAIR * D_MODEL * 4;

    hipMemsetAsync(counts, 0, 256, stream);

    router_kernel<<<T_TOK / 4, 256, 0, stream>>>(x, Wg, top_e, top_w, counts);
    offsets_kernel<<<1, 64, 0, stream>>>(counts, offsets);
    scatter_kernel<<<T_TOK / 256, 256, 0, stream>>>(top_e, offsets, counts2, pair_id);

    cast_x_kernel<<<(T_TOK * D_MODEL) / (256 * 8), 256, 0, stream>>>(x, xb);
    // W1: [E][1024][4096] -> W1T [E][4096][1024]
    transpose_cast_kernel<<<dim3(D_FF / 64, D_MODEL / 64, N_EXPERTS), 256, 0, stream>>>(
        W1, W1T, D_MODEL, D_FF);
    // W2: [E][4096][1024] -> W2T [E][1024][4096]
    transpose_cast_kernel<<<dim3(D_MODEL / 64, D_FF / 64, N_EXPERTS), 256, 0, stream>>>(
        W2, W2T, D_FF, D_MODEL);

    gemm1_mfma<<<dim3(D_FF / 128, N_EXPERTS * MT_MAX), 256, 0, stream>>>(
        xb, W1T, b1, offsets, pair_id, h);
    gemm2_mfma<<<dim3(D_MODEL / 128, N_EXPERTS * MT_MAX), 256, 0, stream>>>(
        h, W2T, b2, offsets, pair_id, y);
    combine_kernel<<<T_TOK, 256, 0, stream>>>(y, top_w, out);
}